// Round 1
// baseline (1000.507 us; speedup 1.0000x reference)
//
#include <hip/hip_runtime.h>
#include <cstddef>

#define LL 512
#define CC 32
#define NF1D 46
#define NF2D 44
#define KK 64
#define LBLK 16

// ---------------- tiny zero kernel (stats re-init each call) ----------------
__global__ void zero_kernel(float* __restrict__ p, int n) {
    int i = blockIdx.x * blockDim.x + threadIdx.x;
    if (i < n) p[i] = 0.0f;
}

// ---------------- tower: conv1 stage (resblock rb) ----------------
// staging computes x_rb on the fly: rb==0 -> proj(t1d); rb>0 -> elu(xprev + norm(zg))
// writes x_rb (own slice) to xout, y_raw = conv1(x_rb) to yg, per-channel stats to stats_y
__global__ __launch_bounds__(256) void conv_a_kernel(
    const float* __restrict__ t1d, const float* __restrict__ w1d,
    const float* __restrict__ b1d, const float* __restrict__ xprev,
    const float* __restrict__ zg, const float* __restrict__ stats_prev,
    const float* __restrict__ cw, float* __restrict__ xout,
    float* __restrict__ yg, float* __restrict__ stats_y, int first)
{
    __shared__ float xs[18 * 32];
    __shared__ float wl[3072];
    __shared__ float mc[32], vc[32];
    __shared__ float ssum[32], ssq[32];
    int tid = threadIdx.x;
    int bt = blockIdx.x >> 5;
    int l0 = (blockIdx.x & 31) * LBLK;

    if (tid < 32) {
        ssum[tid] = 0.f; ssq[tid] = 0.f;
        if (!first) {
            float s = stats_prev[bt * 64 + tid * 2];
            float q = stats_prev[bt * 64 + tid * 2 + 1];
            float m = s * (1.0f / 512.0f);
            float v = q * (1.0f / 512.0f) - m * m;
            mc[tid] = m;
            vc[tid] = rsqrtf(v + 1e-5f);
        }
    }
    // stage conv weights transposed: wl[(ic*3+k)*32 + oc]
    for (int t = tid; t < 3072; t += 256) {
        int oc = t / 96, rem = t - oc * 96;
        wl[rem * 32 + oc] = cw[t];
    }
    __syncthreads();

    // stage x (own 16 positions + halo) into LDS
    for (int idx = tid; idx < 18 * 32; idx += 256) {
        int c = idx & 31, ll = idx >> 5;
        int l = l0 - 1 + ll;
        float val = 0.f;
        if (l >= 0 && l < LL) {
            if (first) {
                const float* tr = t1d + (size_t)(bt * LL + l) * NF1D;
                const float* wr = w1d + c * NF1D;
                float a = b1d[c];
                for (int f = 0; f < NF1D; ++f) a = fmaf(tr[f], wr[f], a);
                val = a;
            } else {
                int g = (bt * LL + l) * CC + c;
                float a = xprev[g] + (zg[g] - mc[c]) * vc[c];
                val = a > 0.f ? a : (expf(a) - 1.f);
            }
            if (ll >= 1 && ll <= LBLK) xout[(bt * LL + l) * CC + c] = val;
        }
        xs[ll * 32 + c] = val;
    }
    __syncthreads();

    int oc = tid & 31;
    int lpb = tid >> 5;
    for (int p = 0; p < 2; ++p) {
        int lpos = p * 8 + lpb;
        float acc = 0.f;
        for (int icn = 0; icn < CC; ++icn) {
            float x0 = xs[lpos * 32 + icn];
            float x1 = xs[(lpos + 1) * 32 + icn];
            float x2 = xs[(lpos + 2) * 32 + icn];
            acc = fmaf(x0, wl[(icn * 3 + 0) * 32 + oc], acc);
            acc = fmaf(x1, wl[(icn * 3 + 1) * 32 + oc], acc);
            acc = fmaf(x2, wl[(icn * 3 + 2) * 32 + oc], acc);
        }
        yg[(bt * LL + l0 + lpos) * CC + oc] = acc;
        atomicAdd(&ssum[oc], acc);
        atomicAdd(&ssq[oc], acc * acc);
    }
    __syncthreads();
    if (tid < 32) {
        atomicAdd(&stats_y[bt * 64 + tid * 2], ssum[tid]);
        atomicAdd(&stats_y[bt * 64 + tid * 2 + 1], ssq[tid]);
    }
}

// ---------------- tower: conv2 stage ----------------
// staging: t = elu(norm(y_raw)); writes z_raw = conv2(t) to zg + stats
__global__ __launch_bounds__(256) void conv_b_kernel(
    const float* __restrict__ yin, const float* __restrict__ stats_y,
    const float* __restrict__ cw, float* __restrict__ zg,
    float* __restrict__ stats_z)
{
    __shared__ float xs[18 * 32];
    __shared__ float wl[3072];
    __shared__ float mc[32], vc[32];
    __shared__ float ssum[32], ssq[32];
    int tid = threadIdx.x;
    int bt = blockIdx.x >> 5;
    int l0 = (blockIdx.x & 31) * LBLK;

    if (tid < 32) {
        ssum[tid] = 0.f; ssq[tid] = 0.f;
        float s = stats_y[bt * 64 + tid * 2];
        float q = stats_y[bt * 64 + tid * 2 + 1];
        float m = s * (1.0f / 512.0f);
        float v = q * (1.0f / 512.0f) - m * m;
        mc[tid] = m;
        vc[tid] = rsqrtf(v + 1e-5f);
    }
    for (int t = tid; t < 3072; t += 256) {
        int oc = t / 96, rem = t - oc * 96;
        wl[rem * 32 + oc] = cw[t];
    }
    __syncthreads();

    for (int idx = tid; idx < 18 * 32; idx += 256) {
        int c = idx & 31, ll = idx >> 5;
        int l = l0 - 1 + ll;
        float val = 0.f;
        if (l >= 0 && l < LL) {
            int g = (bt * LL + l) * CC + c;
            float a = (yin[g] - mc[c]) * vc[c];
            val = a > 0.f ? a : (expf(a) - 1.f);
        }
        xs[ll * 32 + c] = val;
    }
    __syncthreads();

    int oc = tid & 31;
    int lpb = tid >> 5;
    for (int p = 0; p < 2; ++p) {
        int lpos = p * 8 + lpb;
        float acc = 0.f;
        for (int icn = 0; icn < CC; ++icn) {
            float x0 = xs[lpos * 32 + icn];
            float x1 = xs[(lpos + 1) * 32 + icn];
            float x2 = xs[(lpos + 2) * 32 + icn];
            acc = fmaf(x0, wl[(icn * 3 + 0) * 32 + oc], acc);
            acc = fmaf(x1, wl[(icn * 3 + 1) * 32 + oc], acc);
            acc = fmaf(x2, wl[(icn * 3 + 2) * 32 + oc], acc);
        }
        zg[(bt * LL + l0 + lpos) * CC + oc] = acc;
        atomicAdd(&ssum[oc], acc);
        atomicAdd(&ssq[oc], acc * acc);
    }
    __syncthreads();
    if (tid < 32) {
        atomicAdd(&stats_z[bt * 64 + tid * 2], ssum[tid]);
        atomicAdd(&stats_z[bt * 64 + tid * 2 + 1], ssq[tid]);
    }
}

// ---------------- finalize: emb -> leftpe/rightpe (pe + bias folded) ----------------
__global__ __launch_bounds__(256) void finalize_kernel(
    const float* __restrict__ xg, const float* __restrict__ zg,
    const float* __restrict__ stats7, const float* __restrict__ proj_w,
    const float* __restrict__ proj_b, float* __restrict__ leftpe,
    float* __restrict__ rightpe)
{
    __shared__ float emb[8 * 32];
    int tid = threadIdx.x;
    int r0 = blockIdx.x * 8;
    {
        int rl = tid >> 5, c = tid & 31;
        int r = r0 + rl;
        int bt = r >> 9;
        float s = stats7[bt * 64 + c * 2];
        float q = stats7[bt * 64 + c * 2 + 1];
        float m = s * (1.0f / 512.0f);
        float v = q * (1.0f / 512.0f) - m * m;
        float inv = rsqrtf(v + 1e-5f);
        float a = xg[r * 32 + c] + (zg[r * 32 + c] - m) * inv;
        emb[rl * 32 + c] = a > 0.f ? a : (expf(a) - 1.f);
    }
    __syncthreads();
    const float C16 = 0.5756462732485115f;  // ln(10000)/16
    for (int p = 0; p < 2; ++p) {
        int idx = p * 256 + tid;
        int rl = idx >> 6, o = idx & 63;
        int r = r0 + rl;
        int bt = r >> 9, l = r & 511;
        const float* pw = proj_w + o * 109;
        float lacc = 0.f, racc = proj_b[o];
        for (int c = 0; c < CC; ++c) {
            float e = emb[rl * 32 + c];
            lacc = fmaf(e, pw[NF2D + c], lacc);
            racc = fmaf(e, pw[NF2D + CC + c], racc);
        }
        if (bt == 0) {
            int k = o & 31;
            float fl = (float)l;
            float pe;
            if (k < 16) pe = sinf(fl * expf(-(float)k * C16));
            else        pe = cosf(fl * expf(-(float)(k - 16) * C16));
            if (o < 32) lacc += pe; else racc += pe;
        }
        leftpe[r * 64 + o] = lacc;
        rightpe[r * 64 + o] = racc;
    }
}

// ---------------- main pair kernel (memory-bound, 452 MB HBM) ----------------
// block = one (bt,i); lane = output channel; W2d row in 44 VGPRs per lane.
__global__ __launch_bounds__(256) void pair_kernel(
    const float* __restrict__ t2d, const float* __restrict__ proj_w,
    const float* __restrict__ leftpe, const float* __restrict__ rightpe,
    float* __restrict__ out)
{
    int blk = blockIdx.x;           // bt*512 + i
    int lane = threadIdx.x & 63;
    int wave = threadIdx.x >> 6;
    int bt = blk >> 9;
    int i = blk & 511;

    const float* pw = proj_w + lane * 109;
    float w[NF2D];
#pragma unroll
    for (int f = 0; f < NF2D; ++f) w[f] = pw[f];
    float wsep = pw[108];
    float lpe = leftpe[blk * 64 + lane];

    const float4* xbase = (const float4*)(t2d + (size_t)blk * LL * NF2D);
    const float* rbase = rightpe + (size_t)(bt << 9) * 64;
    float* obase = out + (size_t)blk * LL * KK;

    int j0 = wave * 128, j1 = j0 + 128;
#pragma unroll 2
    for (int j = j0; j < j1; ++j) {
        const float4* xr = xbase + j * 11;
        float rv = rbase[j * 64 + lane];
        int d = i - j; d = d < 0 ? -d : d;
        float sepv = __logf((float)(d + 1));
        float acc = fmaf(sepv, wsep, lpe + rv);
#pragma unroll
        for (int q = 0; q < 11; ++q) {
            float4 xv = xr[q];
            acc = fmaf(xv.x, w[4 * q + 0], acc);
            acc = fmaf(xv.y, w[4 * q + 1], acc);
            acc = fmaf(xv.z, w[4 * q + 2], acc);
            acc = fmaf(xv.w, w[4 * q + 3], acc);
        }
        obase[j * 64 + lane] = acc;
    }
}

extern "C" void kernel_launch(void* const* d_in, const int* in_sizes, int n_in,
                              void* d_out, int out_size, void* d_ws, size_t ws_size,
                              hipStream_t stream) {
    const float* t1d = (const float*)d_in[0];
    const float* t2d = (const float*)d_in[1];
    const float* w1d = (const float*)d_in[2];
    const float* b1d = (const float*)d_in[3];
    const float* c1w = (const float*)d_in[4];
    const float* c2w = (const float*)d_in[5];
    const float* pw  = (const float*)d_in[6];
    const float* pb  = (const float*)d_in[7];
    float* out = (float*)d_out;
    float* ws = (float*)d_ws;

    // workspace layout (floats)
    float* xg_a  = ws;                 // 4*512*32 = 65536
    float* xg_b  = ws + 65536;
    float* yg    = ws + 131072;
    float* zg    = ws + 196608;
    float* stats = ws + 262144;        // 8 stages * 256
    float* lpe   = ws + 264192;        // 4*512*64 = 131072
    float* rpe   = ws + 395264;

    zero_kernel<<<8, 256, 0, stream>>>(stats, 2048);

    for (int rb = 0; rb < 4; ++rb) {
        float* sy = stats + (2 * rb) * 256;
        float* sz = stats + (2 * rb + 1) * 256;
        const float* sprev = (rb == 0) ? stats : stats + (2 * rb - 1) * 256;
        const float* xprev = (rb & 1) ? xg_a : xg_b;   // rb1:a, rb2:b, rb3:a
        float* xout = (rb & 1) ? xg_b : xg_a;          // rb0:a, rb1:b, rb2:a, rb3:b
        if (rb == 1 || rb == 3) { xprev = xg_a; xout = xg_b; }
        else if (rb == 2)        { xprev = xg_b; xout = xg_a; }
        conv_a_kernel<<<128, 256, 0, stream>>>(t1d, w1d, b1d, xprev, zg, sprev,
                                               c1w + rb * 3072, xout, yg, sy,
                                               rb == 0 ? 1 : 0);
        conv_b_kernel<<<128, 256, 0, stream>>>(yg, sy, c2w + rb * 3072, zg, sz);
    }
    finalize_kernel<<<256, 256, 0, stream>>>(xg_b, zg, stats + 7 * 256, pw, pb,
                                             lpe, rpe);
    pair_kernel<<<2048, 256, 0, stream>>>(t2d, pw, lpe, rpe, out);
}